// Round 3
// baseline (4656.133 us; speedup 1.0000x reference)
//
#include <hip/hip_runtime.h>
#include <math.h>

#define B 128
#define L 2048
#define H 512
#define D 512
#define NG 2048   // 4*H
#define T 10
#define S 16      // L-chunks per batch row for attention partials
#define GB 256    // gates blocks fused in front of attention blocks

// workspace layout (float offsets); ws_size = 2 GiB
#define OFF_S    ((size_t)0)        // c state (attention query), B*H
#define OFF_H    ((size_t)65536)    // hidden h, B*H
#define OFF_X    ((size_t)131072)   // current x, B*D
#define OFF_SS   ((size_t)196608)   // ||s||^2 per b, B
#define OFF_G    ((size_t)196736)   // gates, B*NG
#define OFF_PL   ((size_t)460928)   // partial l, B*S
#define OFF_PCTX ((size_t)462976)   // partial ctx, B*S*H
#define OFF_RN   ((size_t)1511552)  // 1/||h_l||, B*L
#define OFF_HB   ((size_t)1773696)  // bf16 copy of hid_states, B*L*H bf16
#define OFF_CNT  ((size_t)68882560) // T*B int tickets (right after HB: 1773696 + 128*2048*512/2)

__device__ __forceinline__ float sigf(float x){ return 1.0f / (1.0f + __expf(-x)); }

__device__ __forceinline__ unsigned int b16r(float f){   // fp32 -> bf16 bits, RNE
    unsigned int u = __float_as_uint(f);
    return (u + 0x7FFFu + ((u >> 16) & 1u)) >> 16;
}
__device__ __forceinline__ unsigned int pack2(float lo, float hi){
    return b16r(lo) | (b16r(hi) << 16);
}

#define UNPK(u, f0, f1) { f0 = __uint_as_float((u) << 16); f1 = __uint_as_float((u) & 0xFFFF0000u); }

__device__ __forceinline__ float block_sum256(float v){
    for (int off = 32; off; off >>= 1) v += __shfl_xor(v, off, 64);
    __shared__ float r[4];
    int wave = threadIdx.x >> 6, lane = threadIdx.x & 63;
    if (lane == 0) r[wave] = v;
    __syncthreads();
    return r[0] + r[1] + r[2] + r[3];
}

// ---- init: ss=||s0||^2, zero per-step tickets. s/h/x are read directly from inputs at step 0. ----
__global__ void init_k(const float* __restrict__ s0, float* __restrict__ ws){
    int b = blockIdx.x, t = threadIdx.x;
    float ssq = 0.f;
    for (int h = t; h < H; h += 256){
        float sv = s0[b*H + h];
        ssq += sv * sv;
    }
    float tot = block_sum256(ssq);
    if (t == 0) ws[OFF_SS + b] = tot;
    int* cnt = (int*)(ws + OFF_CNT);
    for (int i = t; i < T; i += 256) cnt[i*B + b] = 0;
}

// ---- load s (pre-scaled by 1/||s||) into 32 regs, 16-lane layout ----
__device__ __forceinline__ void load_snorm(const float* __restrict__ sb_base, float rssb, int g, float* sf){
    const float* sb = sb_base + g * 8;
    #pragma unroll
    for (int cb = 0; cb < 4; cb++){
        float4 a = *(const float4*)(sb + cb*128);
        float4 c = *(const float4*)(sb + cb*128 + 4);
        sf[cb*8+0]=a.x*rssb; sf[cb*8+1]=a.y*rssb; sf[cb*8+2]=a.z*rssb; sf[cb*8+3]=a.w*rssb;
        sf[cb*8+4]=c.x*rssb; sf[cb*8+5]=c.y*rssb; sf[cb*8+6]=c.z*rssb; sf[cb*8+7]=c.w*rssb;
    }
}

// ---- shared epilogue: combine r-groups + waves, write chunk partials ----
__device__ __forceinline__ void attn_epilogue(float* ctx, float lsum, float* smem,
                                              float* __restrict__ ws, int b, int chunk,
                                              int wave, int g, int r){
    #pragma unroll
    for (int k = 0; k < 32; k++){
        ctx[k] += __shfl_xor(ctx[k], 16, 64);
        ctx[k] += __shfl_xor(ctx[k], 32, 64);
    }
    lsum += __shfl_xor(lsum, 16, 64);
    lsum += __shfl_xor(lsum, 32, 64);

    float (*lctx)[512] = (float(*)[512])smem;   // 4*512 floats
    float* ll = smem + 2048;                    // 4 floats
    if (r == 0){
        #pragma unroll
        for (int cb = 0; cb < 4; cb++){
            float4 a = { ctx[cb*8+0], ctx[cb*8+1], ctx[cb*8+2], ctx[cb*8+3] };
            float4 c = { ctx[cb*8+4], ctx[cb*8+5], ctx[cb*8+6], ctx[cb*8+7] };
            *(float4*)&lctx[wave][cb*128 + g*8]     = a;
            *(float4*)&lctx[wave][cb*128 + g*8 + 4] = c;
        }
        if (g == 0) ll[wave] = lsum;
    }
    __syncthreads();
    int t = threadIdx.x;
    float* pc = ws + OFF_PCTX + ((size_t)b * S + chunk) * H;
    pc[t]       = lctx[0][t]     + lctx[1][t]     + lctx[2][t]     + lctx[3][t];
    pc[t + 256] = lctx[0][t+256] + lctx[1][t+256] + lctx[2][t+256] + lctx[3][t+256];
    if (t == 0) ws[OFF_PL + b*S + chunk] = ll[0] + ll[1] + ll[2] + ll[3];
}

// ---- step-0 attention: reads fp32 hid, emits bf16 copy + rn as side effect ----
__device__ __forceinline__ void attn_first_body(const float* __restrict__ hid,
                                                const float* __restrict__ sptr,
                                                float* __restrict__ ws, int bid, float* smem){
    int b = bid >> 4, chunk = bid & (S - 1);
    int wave = threadIdx.x >> 6, lane = threadIdx.x & 63;
    int g = lane & 15, r = lane >> 4;
    float sf[32];
    load_snorm(sptr + (size_t)b * H, rsqrtf(ws[OFF_SS + b]), g, sf);

    int l0w = chunk * 128 + wave * 32;
    const float* hsrc = hid + ((size_t)b * L + l0w) * H + g * 8;
    uint4* hbdst = (uint4*)(ws + OFF_HB) + ((size_t)b * L + l0w) * 64 + g;
    float* rnw = ws + OFF_RN + (size_t)b * L + l0w;

    float ctx[32];
    #pragma unroll
    for (int k = 0; k < 32; k++) ctx[k] = 0.f;
    float lsum = 0.f;

    for (int it = 0; it < 8; it++){
        int ro = it*4 + r;
        const float* src = hsrc + (size_t)ro * H;
        float f[32];
        #pragma unroll
        for (int cb = 0; cb < 4; cb++){
            float4 a = *(const float4*)(src + cb*128);
            float4 c = *(const float4*)(src + cb*128 + 4);
            f[cb*8+0]=a.x; f[cb*8+1]=a.y; f[cb*8+2]=a.z; f[cb*8+3]=a.w;
            f[cb*8+4]=c.x; f[cb*8+5]=c.y; f[cb*8+6]=c.z; f[cb*8+7]=c.w;
        }
        float sq = 0.f, dot = 0.f;
        #pragma unroll
        for (int k = 0; k < 32; k++){ sq += f[k]*f[k]; dot += f[k]*sf[k]; }
        sq  += __shfl_xor(sq, 1, 64);  sq  += __shfl_xor(sq, 2, 64);
        sq  += __shfl_xor(sq, 4, 64);  sq  += __shfl_xor(sq, 8, 64);
        dot += __shfl_xor(dot, 1, 64); dot += __shfl_xor(dot, 2, 64);
        dot += __shfl_xor(dot, 4, 64); dot += __shfl_xor(dot, 8, 64);
        float rnv = rsqrtf(sq);
        if (g == 0) rnw[ro] = rnv;
        uint4* drow = hbdst + (size_t)ro * 64;
        #pragma unroll
        for (int cb = 0; cb < 4; cb++){
            uint4 o;
            o.x = pack2(f[cb*8+0], f[cb*8+1]);
            o.y = pack2(f[cb*8+2], f[cb*8+3]);
            o.z = pack2(f[cb*8+4], f[cb*8+5]);
            o.w = pack2(f[cb*8+6], f[cb*8+7]);
            drow[cb*16] = o;
        }
        float p = __expf(dot * rnv);          // cosine score in [-1,1] -> no max needed
        lsum += p;
        #pragma unroll
        for (int k = 0; k < 32; k++) ctx[k] += p * f[k];
    }
    attn_epilogue(ctx, lsum, smem, ws, b, chunk, wave, g, r);
}

// ---- steady-state attention on bf16 copy ----
__device__ __forceinline__ void attn_steady_body(const float* __restrict__ sptr,
                                                 float* __restrict__ ws, int bid, float* smem){
    int b = bid >> 4, chunk = bid & (S - 1);
    int wave = threadIdx.x >> 6, lane = threadIdx.x & 63;
    int g = lane & 15, r = lane >> 4;
    float sf[32];
    load_snorm(sptr + (size_t)b * H, rsqrtf(ws[OFF_SS + b]), g, sf);

    int l0w = chunk * 128 + wave * 32;
    const uint4* hbu = (const uint4*)(ws + OFF_HB) + ((size_t)b * L + l0w) * 64 + g;
    const float* rnp = ws + OFF_RN + (size_t)b * L + l0w;

    float ctx[32];
    #pragma unroll
    for (int k = 0; k < 32; k++) ctx[k] = 0.f;
    float lsum = 0.f;

    for (int it = 0; it < 8; it++){
        int ro = it*4 + r;
        const uint4* hr = hbu + (size_t)ro * 64;
        uint4 u0 = hr[0];
        uint4 u1 = hr[16];
        uint4 u2 = hr[32];
        uint4 u3 = hr[48];
        float rnv = rnp[ro];
        float f[32];
        UNPK(u0.x, f[0], f[1])   UNPK(u0.y, f[2], f[3])
        UNPK(u0.z, f[4], f[5])   UNPK(u0.w, f[6], f[7])
        UNPK(u1.x, f[8], f[9])   UNPK(u1.y, f[10], f[11])
        UNPK(u1.z, f[12], f[13]) UNPK(u1.w, f[14], f[15])
        UNPK(u2.x, f[16], f[17]) UNPK(u2.y, f[18], f[19])
        UNPK(u2.z, f[20], f[21]) UNPK(u2.w, f[22], f[23])
        UNPK(u3.x, f[24], f[25]) UNPK(u3.y, f[26], f[27])
        UNPK(u3.z, f[28], f[29]) UNPK(u3.w, f[30], f[31])
        float dot = 0.f;
        #pragma unroll
        for (int k = 0; k < 32; k++) dot += f[k] * sf[k];
        dot += __shfl_xor(dot, 1, 64);
        dot += __shfl_xor(dot, 2, 64);
        dot += __shfl_xor(dot, 4, 64);
        dot += __shfl_xor(dot, 8, 64);
        float p = __expf(dot * rnv);
        lsum += p;
        #pragma unroll
        for (int k = 0; k < 32; k++) ctx[k] += p * f[k];
    }
    attn_epilogue(ctx, lsum, smem, ws, b, chunk, wave, g, r);
}

// ---- gates = x @ W_ih + h @ W_hh + b ; outer-product, each weight read ONCE per block ----
__device__ __forceinline__ void gates_body(const float* __restrict__ Wih,
                                           const float* __restrict__ Whh,
                                           const float* __restrict__ bias,
                                           const float* __restrict__ xp,
                                           const float* __restrict__ hp,
                                           float* __restrict__ ws,
                                           float* smem, int gid){
    int tid = threadIdx.x;
    int b0 = (gid >> 4) * 8, n0 = (gid & 15) * 128;
    float* xs  = smem;          // [8][512]
    float* hsm = smem + 4096;   // [8][512]
    {
        int r = tid >> 5, c = (tid & 31) * 16;
        const float* xsrc = xp + (size_t)(b0 + r) * D + c;
        const float* hsrc = hp + (size_t)(b0 + r) * H + c;
        #pragma unroll
        for (int j = 0; j < 4; j++){
            *(float4*)&xs[r*512 + c + j*4]  = *(const float4*)(xsrc + j*4);
            *(float4*)&hsm[r*512 + c + j*4] = *(const float4*)(hsrc + j*4);
        }
    }
    __syncthreads();
    int nt = tid & 31, kh = tid >> 5;
    int n = n0 + nt * 4;
    float4 acc[8];
    #pragma unroll
    for (int bi = 0; bi < 8; bi++){ acc[bi].x = 0.f; acc[bi].y = 0.f; acc[bi].z = 0.f; acc[bi].w = 0.f; }
    const float* w1p = Wih + (size_t)(kh * 64) * NG + n;
    const float* w2p = Whh + (size_t)(kh * 64) * NG + n;
    const float* xk = xs  + kh * 64;
    const float* hk = hsm + kh * 64;
    #pragma unroll 2
    for (int k = 0; k < 64; k++){
        float4 w1 = *(const float4*)(w1p + (size_t)k * NG);
        float4 w2 = *(const float4*)(w2p + (size_t)k * NG);
        #pragma unroll
        for (int bi = 0; bi < 8; bi++){
            float xv = xk[bi*512 + k], hv = hk[bi*512 + k];
            acc[bi].x += xv*w1.x + hv*w2.x;
            acc[bi].y += xv*w1.y + hv*w2.y;
            acc[bi].z += xv*w1.z + hv*w2.z;
            acc[bi].w += xv*w1.w + hv*w2.w;
        }
    }
    __syncthreads();                         // all LDS reads done before realias
    float4* red = (float4*)smem;             // [8 kh][8 bi][32 nt] = 8192 floats
    #pragma unroll
    for (int bi = 0; bi < 8; bi++) red[(kh*8 + bi)*32 + nt] = acc[bi];
    __syncthreads();
    int bi2 = tid >> 5, nt2 = tid & 31;
    int n2 = n0 + nt2 * 4;
    float4 s = *(const float4*)(bias + n2);
    #pragma unroll
    for (int k2 = 0; k2 < 8; k2++){
        float4 p = red[(k2*8 + bi2)*32 + nt2];
        s.x += p.x; s.y += p.y; s.z += p.z; s.w += p.w;
    }
    *(float4*)(ws + OFF_G + (size_t)(b0 + bi2)*NG + n2) = s;
}

// ---- inline tail (256 threads): combine + LSTM cell + MLP head + scatter for one batch ----
__device__ __forceinline__ void tail_body(const float* __restrict__ W1, const float* __restrict__ b1,
                                          const float* __restrict__ W2, const float* __restrict__ b2,
                                          const float* __restrict__ sread,
                                          float* __restrict__ ws, float* __restrict__ out,
                                          int st, int b, float* smem){
    int t = threadIdx.x;
    float* hl  = smem;        // 512
    float* prt = smem + 512;  // 4*64
    float* t1  = smem + 768;  // 64
    float* rr  = smem + 832;  // 4
    __syncthreads();          // previous smem users done

    float Ls = 0.f;
    #pragma unroll
    for (int i = 0; i < S; i++) Ls += ws[OFF_PL + b*S + i];
    float inv = 1.0f / Ls;

    const float* g = ws + OFF_G + (size_t)b * NG;
    float csq = 0.f;
    #pragma unroll
    for (int half = 0; half < 2; half++){
        int idx = half*256 + t;
        float cx = 0.f;
        #pragma unroll
        for (int i = 0; i < S; i++) cx += ws[OFF_PCTX + ((size_t)b*S + i)*H + idx];
        float sn = sread[(size_t)b*H + idx] + cx * inv;
        float gi = g[idx], gf = g[512 + idx], gg = g[1024 + idx], go = g[1536 + idx];
        float c  = sigf(gf) * sn + sigf(gi) * tanhf(gg);
        float hv = sigf(go) * tanhf(c);
        ws[OFF_S + (size_t)b*H + idx] = c;
        ws[OFF_H + (size_t)b*H + idx] = hv;
        hl[idx] = hv;
        csq += c * c;
    }
    for (int off = 32; off; off >>= 1) csq += __shfl_xor(csq, off, 64);
    int wv = t >> 6, ln = t & 63;
    if (ln == 0) rr[wv] = csq;
    __syncthreads();          // covers hl writes too
    if (t == 0) ws[OFF_SS + b] = rr[0] + rr[1] + rr[2] + rr[3];

    // MLP layer 1: 4-way k-split (128 each) x 64 outputs
    int j = t & 63, q = t >> 6;
    float a = 0.f;
    #pragma unroll 4
    for (int k = q*128; k < q*128 + 128; k++) a += hl[k] * W1[k*64 + j];
    prt[q*64 + j] = a;
    __syncthreads();
    if (t < 64){
        float v = b1[t] + prt[t] + prt[64 + t] + prt[128 + t] + prt[192 + t];
        t1[t] = v > 0.f ? v : 0.01f * v;
    }
    __syncthreads();
    // MLP layer 2: two outputs per thread
    #pragma unroll
    for (int half = 0; half < 2; half++){
        int d = half*256 + t;
        float a2 = b2[d];
        #pragma unroll 8
        for (int k = 0; k < 64; k++) a2 += t1[k] * W2[k*512 + d];
        ws[OFF_X + (size_t)b*D + d] = a2;
        int idx = st * D + d;
        out[(size_t)b * (D*T) + (size_t)(idx % T) * D + (idx / T)] = a2;
    }
    __syncthreads();          // smem reusable by next tail iteration
}

// ---- ticket: 32 contributors per batch (16 attn chunks + 16 gates tiles of its octet).
// release-fence -> atomicAdd; last arriver (old==31) runs that batch's tail inline.
__device__ __forceinline__ void ticket_and_tail(const float* __restrict__ W1, const float* __restrict__ b1,
                                                const float* __restrict__ W2, const float* __restrict__ b2,
                                                const float* __restrict__ sread,
                                                float* __restrict__ ws, float* __restrict__ out,
                                                int st, int myb, int b0g, float* smem,
                                                int* nfin_sh, int* finb_sh){
    __syncthreads();      // all waves' stores issued
    __threadfence();      // per-wave release: drain + L2 writeback (cross-XCD visibility)
    __syncthreads();      // all waves' fences complete before the atomic
    if (threadIdx.x == 0){
        int* cnt = (int*)(ws + OFF_CNT) + st * B;
        int nf = 0;
        if (b0g >= 0){
            #pragma unroll
            for (int i = 0; i < 8; i++){
                int old = atomicAdd(&cnt[b0g + i], 1);
                if (old == 31) finb_sh[nf++] = b0g + i;
            }
        } else {
            int old = atomicAdd(&cnt[myb], 1);
            if (old == 31) finb_sh[nf++] = myb;
        }
        *nfin_sh = nf;
    }
    __syncthreads();
    int nf = *nfin_sh;
    if (nf > 0){
        __threadfence();  // acquire side
        for (int i = 0; i < nf; i++)
            tail_body(W1, b1, W2, b2, sread, ws, out, st, finb_sh[i], smem);
    }
}

// ---- one kernel per step: gates (blocks 0..255) + attention (256..2303) + inline tails ----
__global__ __launch_bounds__(256, 3) void step0_k(const float* __restrict__ hid,
                                                  const float* __restrict__ batch,
                                                  const float* __restrict__ h0,
                                                  const float* __restrict__ s0,
                                                  const float* __restrict__ Wih,
                                                  const float* __restrict__ Whh,
                                                  const float* __restrict__ bias,
                                                  const float* __restrict__ W1, const float* __restrict__ b1,
                                                  const float* __restrict__ W2, const float* __restrict__ b2,
                                                  float* __restrict__ ws, float* __restrict__ out){
    __shared__ float smem[8192];
    __shared__ int nfin; __shared__ int finb[8];
    int myb = -1, b0g = -1;
    if (blockIdx.x < GB){
        b0g = ((int)blockIdx.x >> 4) * 8;
        gates_body(Wih, Whh, bias, batch, h0, ws, smem, blockIdx.x);
    } else {
        int bid = blockIdx.x - GB;
        myb = bid >> 4;
        attn_first_body(hid, s0, ws, bid, smem);
    }
    ticket_and_tail(W1, b1, W2, b2, s0, ws, out, 0, myb, b0g, smem, &nfin, finb);
}

__global__ __launch_bounds__(256, 3) void stepN_k(const float* __restrict__ Wih,
                                                  const float* __restrict__ Whh,
                                                  const float* __restrict__ bias,
                                                  const float* __restrict__ W1, const float* __restrict__ b1,
                                                  const float* __restrict__ W2, const float* __restrict__ b2,
                                                  float* __restrict__ ws, float* __restrict__ out, int st){
    __shared__ float smem[8192];
    __shared__ int nfin; __shared__ int finb[8];
    int myb = -1, b0g = -1;
    if (blockIdx.x < GB){
        b0g = ((int)blockIdx.x >> 4) * 8;
        gates_body(Wih, Whh, bias, ws + OFF_X, ws + OFF_H, ws, smem, blockIdx.x);
    } else {
        int bid = blockIdx.x - GB;
        myb = bid >> 4;
        attn_steady_body(ws + OFF_S, ws, bid, smem);
    }
    ticket_and_tail(W1, b1, W2, b2, ws + OFF_S, ws, out, st, myb, b0g, smem, &nfin, finb);
}

extern "C" void kernel_launch(void* const* d_in, const int* in_sizes, int n_in,
                              void* d_out, int out_size, void* d_ws, size_t ws_size,
                              hipStream_t stream) {
    const float* batch = (const float*)d_in[0];
    const float* hid   = (const float*)d_in[1];
    const float* h0    = (const float*)d_in[2];
    const float* s0    = (const float*)d_in[3];
    const float* Wih   = (const float*)d_in[4];
    const float* Whh   = (const float*)d_in[5];
    const float* bl    = (const float*)d_in[6];
    const float* W1    = (const float*)d_in[7];
    const float* b1    = (const float*)d_in[8];
    const float* W2    = (const float*)d_in[9];
    const float* b2    = (const float*)d_in[10];
    float* out = (float*)d_out;
    float* ws  = (float*)d_ws;

    init_k<<<B, 256, 0, stream>>>(s0, ws);
    step0_k<<<B*S + GB, 256, 0, stream>>>(hid, batch, h0, s0, Wih, Whh, bl, W1, b1, W2, b2, ws, out);
    for (int st = 1; st < T; st++)
        stepN_k<<<B*S + GB, 256, 0, stream>>>(Wih, Whh, bl, W1, b1, W2, b2, ws, out, st);
}

// Round 4
// 1639.962 us; speedup vs baseline: 2.8392x; 2.8392x over previous
//
#include <hip/hip_runtime.h>
#include <math.h>

#define B 128
#define L 2048
#define H 512
#define D 512
#define NG 2048   // 4*H
#define T 10
#define S 16      // L-chunks per batch row for attention partials
#define GB 256    // gates blocks fused in front of attention blocks

// parity double-buffered workspace layout (float offsets)
#define OFF_SB(p)   ((size_t)(p)*65536)                      // c-carry, B*H
#define OFF_G(p)    ((size_t)131072 + (size_t)(p)*262144)    // gates, B*NG
#define OFF_PL(p)   ((size_t)655360 + (size_t)(p)*2048)      // partial l, B*S
#define OFF_PCTX(p) ((size_t)659456 + (size_t)(p)*1048576)   // partial ctx, B*S*H
#define OFF_RN      ((size_t)2756608)                        // 1/||h_l||, B*L
#define OFF_HB      ((size_t)3018752)                        // bf16 hid copy, B*L*H bf16

__device__ __forceinline__ float sigf(float x){ return 1.0f / (1.0f + __expf(-x)); }

__device__ __forceinline__ unsigned int b16r(float f){
    unsigned int u = __float_as_uint(f);
    return (u + 0x7FFFu + ((u >> 16) & 1u)) >> 16;
}
__device__ __forceinline__ unsigned int pack2(float lo, float hi){
    return b16r(lo) | (b16r(hi) << 16);
}

#define UNPK(u, f0, f1) { f0 = __uint_as_float((u) << 16); f1 = __uint_as_float((u) & 0xFFFF0000u); }

__device__ __forceinline__ float block_sum256(float v, float* r4){
    for (int off = 32; off; off >>= 1) v += __shfl_xor(v, off, 64);
    int wave = threadIdx.x >> 6, lane = threadIdx.x & 63;
    if (lane == 0) r4[wave] = v;
    __syncthreads();
    return r4[0] + r4[1] + r4[2] + r4[3];
}

__device__ __forceinline__ void load_snorm(const float* sptr, float rssb, int g, float* sf){
    const float* sb = sptr + g * 8;
    #pragma unroll
    for (int cb = 0; cb < 4; cb++){
        float4 a = *(const float4*)(sb + cb*128);
        float4 c = *(const float4*)(sb + cb*128 + 4);
        sf[cb*8+0]=a.x*rssb; sf[cb*8+1]=a.y*rssb; sf[cb*8+2]=a.z*rssb; sf[cb*8+3]=a.w*rssb;
        sf[cb*8+4]=c.x*rssb; sf[cb*8+5]=c.y*rssb; sf[cb*8+6]=c.z*rssb; sf[cb*8+7]=c.w*rssb;
    }
}

__device__ __forceinline__ void attn_epilogue(float* ctx, float lsum, float* smem,
                                              float* __restrict__ pl, float* __restrict__ pc,
                                              int wave, int g, int r){
    #pragma unroll
    for (int k = 0; k < 32; k++){
        ctx[k] += __shfl_xor(ctx[k], 16, 64);
        ctx[k] += __shfl_xor(ctx[k], 32, 64);
    }
    lsum += __shfl_xor(lsum, 16, 64);
    lsum += __shfl_xor(lsum, 32, 64);

    float (*lctx)[512] = (float(*)[512])(smem + 520);
    float* ll = smem + 520 + 2048;
    if (r == 0){
        #pragma unroll
        for (int cb = 0; cb < 4; cb++){
            float4 a = { ctx[cb*8+0], ctx[cb*8+1], ctx[cb*8+2], ctx[cb*8+3] };
            float4 c = { ctx[cb*8+4], ctx[cb*8+5], ctx[cb*8+6], ctx[cb*8+7] };
            *(float4*)&lctx[wave][cb*128 + g*8]     = a;
            *(float4*)&lctx[wave][cb*128 + g*8 + 4] = c;
        }
        if (g == 0) ll[wave] = lsum;
    }
    __syncthreads();
    int t = threadIdx.x;
    pc[t]       = lctx[0][t]     + lctx[1][t]     + lctx[2][t]     + lctx[3][t];
    pc[t + 256] = lctx[0][t+256] + lctx[1][t+256] + lctx[2][t+256] + lctx[3][t+256];
    if (t == 0) pl[0] = ll[0] + ll[1] + ll[2] + ll[3];
}

__device__ __forceinline__ void attn_main_first(const float* __restrict__ hid,
                                                const float* sptr, float rssb,
                                                float* __restrict__ ws, float* smem,
                                                float* __restrict__ pl, float* __restrict__ pc,
                                                int b, int chunk){
    int wave = threadIdx.x >> 6, lane = threadIdx.x & 63;
    int g = lane & 15, r = lane >> 4;
    float sf[32];
    load_snorm(sptr, rssb, g, sf);

    int l0w = chunk * 128 + wave * 32;
    const float* hsrc = hid + ((size_t)b * L + l0w) * H + g * 8;
    uint4* hbdst = (uint4*)(ws + OFF_HB) + ((size_t)b * L + l0w) * 64 + g;
    float* rnw = ws + OFF_RN + (size_t)b * L + l0w;

    float ctx[32];
    #pragma unroll
    for (int k = 0; k < 32; k++) ctx[k] = 0.f;
    float lsum = 0.f;

    for (int it = 0; it < 8; it++){
        int ro = it*4 + r;
        const float* src = hsrc + (size_t)ro * H;
        float f[32];
        #pragma unroll
        for (int cb = 0; cb < 4; cb++){
            float4 a = *(const float4*)(src + cb*128);
            float4 c = *(const float4*)(src + cb*128 + 4);
            f[cb*8+0]=a.x; f[cb*8+1]=a.y; f[cb*8+2]=a.z; f[cb*8+3]=a.w;
            f[cb*8+4]=c.x; f[cb*8+5]=c.y; f[cb*8+6]=c.z; f[cb*8+7]=c.w;
        }
        float sq = 0.f, dot = 0.f;
        #pragma unroll
        for (int k = 0; k < 32; k++){ sq += f[k]*f[k]; dot += f[k]*sf[k]; }
        sq  += __shfl_xor(sq, 1, 64);  sq  += __shfl_xor(sq, 2, 64);
        sq  += __shfl_xor(sq, 4, 64);  sq  += __shfl_xor(sq, 8, 64);
        dot += __shfl_xor(dot, 1, 64); dot += __shfl_xor(dot, 2, 64);
        dot += __shfl_xor(dot, 4, 64); dot += __shfl_xor(dot, 8, 64);
        float rnv = rsqrtf(sq);
        if (g == 0) rnw[ro] = rnv;
        uint4* drow = hbdst + (size_t)ro * 64;
        #pragma unroll
        for (int cb = 0; cb < 4; cb++){
            uint4 o;
            o.x = pack2(f[cb*8+0], f[cb*8+1]);
            o.y = pack2(f[cb*8+2], f[cb*8+3]);
            o.z = pack2(f[cb*8+4], f[cb*8+5]);
            o.w = pack2(f[cb*8+6], f[cb*8+7]);
            drow[cb*16] = o;
        }
        float p = __expf(dot * rnv);
        lsum += p;
        #pragma unroll
        for (int k = 0; k < 32; k++) ctx[k] += p * f[k];
    }
    attn_epilogue(ctx, lsum, smem, pl, pc, wave, g, r);
}

__device__ __forceinline__ void attn_main_steady(const float* sptr, float rssb,
                                                 const float* __restrict__ ws, float* smem,
                                                 float* __restrict__ pl, float* __restrict__ pc,
                                                 int b, int chunk){
    int wave = threadIdx.x >> 6, lane = threadIdx.x & 63;
    int g = lane & 15, r = lane >> 4;
    float sf[32];
    load_snorm(sptr, rssb, g, sf);

    int l0w = chunk * 128 + wave * 32;
    const uint4* hbu = (const uint4*)(ws + OFF_HB) + ((size_t)b * L + l0w) * 64 + g;
    const float* rnp = ws + OFF_RN + (size_t)b * L + l0w;

    float ctx[32];
    #pragma unroll
    for (int k = 0; k < 32; k++) ctx[k] = 0.f;
    float lsum = 0.f;

    for (int it = 0; it < 8; it++){
        int ro = it*4 + r;
        const uint4* hr = hbu + (size_t)ro * 64;
        uint4 u0 = hr[0];
        uint4 u1 = hr[16];
        uint4 u2 = hr[32];
        uint4 u3 = hr[48];
        float rnv = rnp[ro];
        float f[32];
        UNPK(u0.x, f[0], f[1])   UNPK(u0.y, f[2], f[3])
        UNPK(u0.z, f[4], f[5])   UNPK(u0.w, f[6], f[7])
        UNPK(u1.x, f[8], f[9])   UNPK(u1.y, f[10], f[11])
        UNPK(u1.z, f[12], f[13]) UNPK(u1.w, f[14], f[15])
        UNPK(u2.x, f[16], f[17]) UNPK(u2.y, f[18], f[19])
        UNPK(u2.z, f[20], f[21]) UNPK(u2.w, f[22], f[23])
        UNPK(u3.x, f[24], f[25]) UNPK(u3.y, f[26], f[27])
        UNPK(u3.z, f[28], f[29]) UNPK(u3.w, f[30], f[31])
        float dot = 0.f;
        #pragma unroll
        for (int k = 0; k < 32; k++) dot += f[k] * sf[k];
        dot += __shfl_xor(dot, 1, 64);
        dot += __shfl_xor(dot, 2, 64);
        dot += __shfl_xor(dot, 4, 64);
        dot += __shfl_xor(dot, 8, 64);
        float p = __expf(dot * rnv);
        lsum += p;
        #pragma unroll
        for (int k = 0; k < 32; k++) ctx[k] += p * f[k];
    }
    attn_epilogue(ctx, lsum, smem, pl, pc, wave, g, r);
}

__global__ __launch_bounds__(256, 3) void step_k(const float* __restrict__ hid,
                                                 const float* __restrict__ batch,
                                                 const float* __restrict__ h0,
                                                 const float* __restrict__ s0,
                                                 const float* __restrict__ Wih,
                                                 const float* __restrict__ Whh,
                                                 const float* __restrict__ bias,
                                                 const float* __restrict__ W1, const float* __restrict__ b1,
                                                 const float* __restrict__ W2, const float* __restrict__ b2,
                                                 float* __restrict__ ws, float* __restrict__ out, int st){
    __shared__ float smem[8704];
    const int par = st & 1, q = par ^ 1;
    int tid = threadIdx.x;

    if (blockIdx.x < GB){
        int gid = blockIdx.x;
        int b0 = (gid >> 4) * 8, ntile = gid & 15, n0 = ntile * 128;
        float* xs  = smem;          // [8][512]
        float* hsm = smem + 4096;   // [8][512]
        float* t1s = smem + 8192;   // [8][64]

        if (st == 0){
            int r = tid >> 5, c = (tid & 31) * 16;
            #pragma unroll
            for (int j = 0; j < 4; j++){
                *(float4*)&xs[r*512 + c + j*4]  = *(const float4*)(batch + (size_t)(b0 + r)*D + c + j*4);
                *(float4*)&hsm[r*512 + c + j*4] = *(const float4*)(h0 + (size_t)(b0 + r)*H + c + j*4);
            }
        } else {
            int bi = tid >> 5, u = tid & 31;
            int b = b0 + bi;
            const float* plq = ws + OFF_PL(q) + b*S;
            float Ls = 0.f;
            #pragma unroll
            for (int i = 0; i < S; i++) Ls += plq[i];
            float inv = 1.0f / Ls;
            float cx[16];
            #pragma unroll
            for (int e = 0; e < 16; e++) cx[e] = 0.f;
            #pragma unroll 2
            for (int i = 0; i < S; i++){
                const float* p = ws + OFF_PCTX(q) + ((size_t)(b*S + i))*H + u*16;
                #pragma unroll
                for (int e4 = 0; e4 < 4; e4++){
                    float4 v = *(const float4*)(p + e4*4);
                    cx[e4*4+0] += v.x; cx[e4*4+1] += v.y; cx[e4*4+2] += v.z; cx[e4*4+3] += v.w;
                }
            }
            const float* gg = ws + OFF_G(q) + (size_t)b * NG;
            const float* sprev = (st == 1 ? s0 : ws + OFF_SB(q)) + (size_t)b * H;
            #pragma unroll
            for (int e = 0; e < 16; e++){
                int idx = u*16 + e;
                float sn = sprev[idx] + cx[e]*inv;
                float c  = sigf(gg[512 + idx]) * sn + sigf(gg[idx]) * tanhf(gg[1024 + idx]);
                hsm[bi*512 + idx] = sigf(gg[1536 + idx]) * tanhf(c);
            }
            __syncthreads();
            float a0 = 0.f, a1 = 0.f;
            for (int k = 0; k < 512; k++){
                float hv = hsm[bi*512 + k];
                a0 += hv * W1[k*64 + u];
                a1 += hv * W1[k*64 + u + 32];
            }
            a0 += b1[u]; a1 += b1[u + 32];
            t1s[bi*64 + u]      = a0 > 0.f ? a0 : 0.01f*a0;
            t1s[bi*64 + u + 32] = a1 > 0.f ? a1 : 0.01f*a1;
            __syncthreads();
            float xacc[16];
            #pragma unroll
            for (int e = 0; e < 16; e++) xacc[e] = b2[u*16 + e];
            for (int k = 0; k < 64; k++){
                float tv = t1s[bi*64 + k];
                const float* wp = W2 + (size_t)k*512 + u*16;
                #pragma unroll
                for (int e4 = 0; e4 < 4; e4++){
                    float4 wv = *(const float4*)(wp + e4*4);
                    xacc[e4*4+0] += tv*wv.x; xacc[e4*4+1] += tv*wv.y;
                    xacc[e4*4+2] += tv*wv.z; xacc[e4*4+3] += tv*wv.w;
                }
            }
            #pragma unroll
            for (int e = 0; e < 16; e++) xs[bi*512 + u*16 + e] = xacc[e];
            if (ntile == 0){
                #pragma unroll
                for (int e = 0; e < 16; e++){
                    int d = u*16 + e;
                    int idx = (st - 1)*D + d;
                    out[(size_t)b*(D*T) + (size_t)(idx % T)*D + (idx / T)] = xacc[e];
                }
            }
        }
        __syncthreads();
        int nt = tid & 31, kh = tid >> 5;
        int n = n0 + nt * 4;
        float4 acc[8];
        #pragma unroll
        for (int bi = 0; bi < 8; bi++){ acc[bi].x = 0.f; acc[bi].y = 0.f; acc[bi].z = 0.f; acc[bi].w = 0.f; }
        const float* w1p = Wih + (size_t)(kh * 64) * NG + n;
        const float* w2p = Whh + (size_t)(kh * 64) * NG + n;
        const float* xk = xs  + kh * 64;
        const float* hk = hsm + kh * 64;
        #pragma unroll 2
        for (int k = 0; k < 64; k++){
            float4 w1 = *(const float4*)(w1p + (size_t)k * NG);
            float4 w2 = *(const float4*)(w2p + (size_t)k * NG);
            #pragma unroll
            for (int bi = 0; bi < 8; bi++){
                float xv = xk[bi*512 + k], hv = hk[bi*512 + k];
                acc[bi].x += xv*w1.x + hv*w2.x;
                acc[bi].y += xv*w1.y + hv*w2.y;
                acc[bi].z += xv*w1.z + hv*w2.z;
                acc[bi].w += xv*w1.w + hv*w2.w;
            }
        }
        __syncthreads();
        float4* red = (float4*)smem;
        #pragma unroll
        for (int bi = 0; bi < 8; bi++) red[(kh*8 + bi)*32 + nt] = acc[bi];
        __syncthreads();
        int bi2 = tid >> 5, nt2 = tid & 31;
        int n2 = n0 + nt2 * 4;
        float4 sg = *(const float4*)(bias + n2);
        #pragma unroll
        for (int k2 = 0; k2 < 8; k2++){
            float4 p = red[(k2*8 + bi2)*32 + nt2];
            sg.x += p.x; sg.y += p.y; sg.z += p.z; sg.w += p.w;
        }
        *(float4*)(ws + OFF_G(par) + (size_t)(b0 + bi2)*NG + n2) = sg;
    } else {
        int bid = blockIdx.x - GB;
        int b = bid >> 4, chunk = bid & (S - 1);
        float* pl = ws + OFF_PL(par) + b*S + chunk;
        float* pc = ws + OFF_PCTX(par) + ((size_t)(b*S + chunk))*H;

        if (st == 0){
            float ssq = 0.f;
            #pragma unroll
            for (int hh = 0; hh < 2; hh++){
                float sv = s0[(size_t)b*H + hh*256 + tid];
                ssq += sv * sv;
            }
            float rssb = rsqrtf(block_sum256(ssq, smem + 8448));
            attn_main_first(hid, s0 + (size_t)b*H, rssb, ws, smem, pl, pc, b, chunk);
        } else {
            float* sc = smem;
            const float* plq = ws + OFF_PL(q) + b*S;
            float Ls = 0.f;
            #pragma unroll
            for (int i = 0; i < S; i++) Ls += plq[i];
            float inv = 1.0f / Ls;
            const float* gg = ws + OFF_G(q) + (size_t)b * NG;
            const float* sprev = (st == 1 ? s0 : ws + OFF_SB(q)) + (size_t)b * H;
            float ssq = 0.f;
            #pragma unroll
            for (int hh = 0; hh < 2; hh++){
                int idx = hh*256 + tid;
                float cxv = 0.f;
                #pragma unroll
                for (int i = 0; i < S; i++) cxv += ws[OFF_PCTX(q) + ((size_t)(b*S + i))*H + idx];
                float sn = sprev[idx] + cxv*inv;
                float c  = sigf(gg[512 + idx]) * sn + sigf(gg[idx]) * tanhf(gg[1024 + idx]);
                sc[idx] = c;
                ssq += c * c;
                if (chunk == 0) ws[OFF_SB(par) + (size_t)b*H + idx] = c;
            }
            float rssb = rsqrtf(block_sum256(ssq, smem + 8448));
            attn_main_steady(sc, rssb, ws, smem, pl, pc, b, chunk);
        }
    }
}

__global__ __launch_bounds__(256) void final_k(const float* __restrict__ W1, const float* __restrict__ b1,
                                               const float* __restrict__ W2, const float* __restrict__ b2,
                                               float* __restrict__ ws, float* __restrict__ out){
    int b = blockIdx.x, tid = threadIdx.x;
    __shared__ float hl[512];
    __shared__ float prt[256];
    __shared__ float t1[64];
    const float* plq = ws + OFF_PL(1) + b*S;
    float Ls = 0.f;
    #pragma unroll
    for (int i = 0; i < S; i++) Ls += plq[i];
    float inv = 1.0f / Ls;
    const float* gg = ws + OFF_G(1) + (size_t)b * NG;
    const float* sprev = ws + OFF_SB(1) + (size_t)b * H;
    #pragma unroll
    for (int hh = 0; hh < 2; hh++){
        int idx = hh*256 + tid;
        float cxv = 0.f;
        #pragma unroll
        for (int i = 0; i < S; i++) cxv += ws[OFF_PCTX(1) + ((size_t)(b*S + i))*H + idx];
        float sn = sprev[idx] + cxv*inv;
        float c  = sigf(gg[512 + idx]) * sn + sigf(gg[idx]) * tanhf(gg[1024 + idx]);
        hl[idx] = sigf(gg[1536 + idx]) * tanhf(c);
    }
    __syncthreads();
    int j = tid & 63, q4 = tid >> 6;
    float a = 0.f;
    #pragma unroll 4
    for (int k = q4*128; k < q4*128 + 128; k++) a += hl[k] * W1[k*64 + j];
    prt[q4*64 + j] = a;
    __syncthreads();
    if (tid < 64){
        float v = b1[tid] + prt[tid] + prt[64 + tid] + prt[128 + tid] + prt[192 + tid];
        t1[tid] = v > 0.f ? v : 0.01f*v;
    }
    __syncthreads();
    #pragma unroll
    for (int hh = 0; hh < 2; hh++){
        int d = hh*256 + tid;
        float a2 = b2[d];
        #pragma unroll 8
        for (int k = 0; k < 64; k++) a2 += t1[k] * W2[k*512 + d];
        int idx = 9*D + d;
        out[(size_t)b*(D*T) + (size_t)(idx % T)*D + (idx / T)] = a2;
    }
}

extern "C" void kernel_launch(void* const* d_in, const int* in_sizes, int n_in,
                              void* d_out, int out_size, void* d_ws, size_t ws_size,
                              hipStream_t stream) {
    const float* batch = (const float*)d_in[0];
    const float* hid   = (const float*)d_in[1];
    const float* h0    = (const float*)d_in[2];
    const float* s0    = (const float*)d_in[3];
    const float* Wih   = (const float*)d_in[4];
    const float* Whh   = (const float*)d_in[5];
    const float* bl    = (const float*)d_in[6];
    const float* W1    = (const float*)d_in[7];
    const float* b1    = (const float*)d_in[8];
    const float* W2    = (const float*)d_in[9];
    const float* b2    = (const float*)d_in[10];
    float* out = (float*)d_out;
    float* ws  = (float*)d_ws;

    for (int st = 0; st < T; st++)
        step_k<<<B*S + GB, 256, 0, stream>>>(hid, batch, h0, s0, Wih, Whh, bl,
                                             W1, b1, W2, b2, ws, out, st);
    final_k<<<B, 256, 0, stream>>>(W1, b1, W2, b2, ws, out);
}